// Round 12
// baseline (72.620 us; speedup 1.0000x reference)
//
#include <hip/hip_runtime.h>

#define IMG_H 512
#define IMG_W 512
#define NB    8
#define TILE  32
#define LROWS 34            // owner rows 0..31 + 2 halo rows below
#define LCOLS 36            // owner col j -> lds col j+2 (halo +-2)
#define NBLK  (NB * (IMG_H / TILE) * (IMG_W / TILE))   // 2048
#define N_MEAN 16777216.0   // B * 8 dirs * H * W
#define REPEAT 8            // DIAGNOSTIC: compute phase x8, acc scaled by 1/8
#define LOG2E 1.44269504f
#define LN2   0.69314718f

__device__ __forceinline__ float frcp(float x){ return __builtin_amdgcn_rcpf(x); }
__device__ __forceinline__ float fexp2(float x){ return __builtin_amdgcn_exp2f(x); }
__device__ __forceinline__ float flog2(float x){ return __builtin_amdgcn_logf(x); }

// Per-pixel pack {s, mw, e', nw}:
//   s  = sigmoid(c_map)
//   mw = (t ? -0.6 : -1.4) * log(sel+1e-4), sel = t ? s : 1-s   (eq-pair num, K=1 weight)
//   e' = (t ? -1 : +1) * exp(-s);  e' == 0  => OOB sentinel
//   nw = (t ? -0.07 : -0.28) * log(sel+1e-4)                    (nbr num, -0.35*k folded)
__global__ __launch_bounds__(256, 8) void scloss_main(
    const float* __restrict__ cmap, const int* __restrict__ tgt,
    float* __restrict__ partials)
{
    __shared__ float4 pack[LROWS * LCOLS];

    const int tilesPerRow = IMG_W / TILE;                 // 16
    const int tilesPerImg = (IMG_H / TILE) * tilesPerRow; // 256
    int blk = blockIdx.x;
    int b   = blk / tilesPerImg;
    int ti  = blk % tilesPerImg;
    int tr  = (ti / tilesPerRow) * TILE;
    int tc  = (ti % tilesPerRow) * TILE;

    const float* cimg = cmap + (size_t)b * (IMG_H * IMG_W);
    const int*   timg = tgt  + (size_t)b * (IMG_H * IMG_W);

    // Stage rows tr..tr+33, cols tc-2..tc+33.
    for (int idx = threadIdx.x; idx < LROWS * LCOLS; idx += 256) {
        int lr = idx / LCOLS, lc = idx - lr * LCOLS;
        int gr = tr + lr, gc = tc + lc - 2;
        float4 v = make_float4(0.0f, 0.0f, 0.0f, 0.0f);
        if (gr < IMG_H && (unsigned)gc < (unsigned)IMG_W) {
            float x = cimg[gr * IMG_W + gc];
            bool  t = timg[gr * IMG_W + gc] != 0;
            float s   = frcp(1.0f + fexp2(x * -LOG2E));
            float sel = t ? s : (1.0f - s);
            float L   = LN2 * flog2(sel + 1e-4f);
            float e   = fexp2(s * -LOG2E);
            v = make_float4(s,
                            (t ? -0.6f : -1.4f) * L,
                            t ? -e : e,
                            (t ? -0.07f : -0.28f) * L);
        }
        pack[idx] = v;
    }
    __syncthreads();

    int j  = threadIdx.x & 31;
    int i0 = threadIdx.x >> 5;      // 0..7 -> owner rows 4*i0..4*i0+3
    float acc = 0.0f;

// One edge, named-scalar outputs only.
#define EDGE(VB, Dd, Nn, WSK, MK) do {                                    \
        float4 vb  = (VB);                                                \
        bool  tb   = vb.z < 0.0f;                                         \
        bool  qpos = (ta == tb);           /* both targets equal */       \
        bool  qnz  = vb.z != 0.0f;         /* neighbor in bounds */       \
        float ppp  = __builtin_fmaf(sa, vb.x, 1e-4f);                     \
        float ompp = __builtin_fmaf(-sa, vb.x, 1.0001f);                  \
        float argc = (qpos && ta) ? ppp : ompp;                           \
        float lg   = flog2(argc);                                         \
        float E    = fexp2(__builtin_fmaf(ppp, -LOG2E, 1e-4f * LOG2E));   \
        float een  = ta ? vb.z : epa;      /* e' of the t=0 endpoint */   \
        float ee   = qpos ? E : een;                                      \
        Dd         = __builtin_fmaf(-LN2, lg, ee);                        \
        float nm   = qpos ? __builtin_fmaf(WSK, vb.y, MK) : (nwa + vb.w); \
        Nn         = qnz ? nm : 0.0f;                                     \
    } while (0)

// 4 divisions with one reciprocal.
#define COMBINE do {                                                      \
        float d01 = D0 * D1, d23 = D2 * D3;                               \
        float R   = frcp(d01 * d23);                                      \
        float n01 = __builtin_fmaf(N1, D0, N0 * D1);                      \
        float n23 = __builtin_fmaf(N3, D2, N2 * D3);                      \
        acc = __builtin_fmaf(__builtin_fmaf(n23, d01, n01 * d23), R, acc);\
    } while (0)

// One pixel: 8 edges (E,SE,S,SW at K=1,2).
#define PIXEL(VA, S1X, S2X, base) do {                                    \
        float4 va_  = (VA);                                               \
        bool  ta  = va_.z < 0.0f;                                         \
        float sa  = va_.x, nwa = va_.w, epa = va_.z;                      \
        float mwa = va_.y, hmw = 0.5f * va_.y;                            \
        float D0, D1, D2, D3, N0, N1, N2, N3;                             \
        EDGE(base[1],           D0, N0, 1.0f, mwa);   /* E  K1 */         \
        EDGE(base[LCOLS + 1],   D1, N1, 1.0f, mwa);   /* SE K1 */         \
        EDGE(S1X,               D2, N2, 1.0f, mwa);   /* S  K1 */         \
        EDGE(base[LCOLS - 1],   D3, N3, 1.0f, mwa);   /* SW K1 */         \
        COMBINE;                                                          \
        EDGE(base[2],           D0, N0, 0.5f, hmw);   /* E  K2 */         \
        EDGE(base[2*LCOLS + 2], D1, N1, 0.5f, hmw);   /* SE K2 */         \
        EDGE(S2X,               D2, N2, 0.5f, hmw);   /* S  K2 */         \
        EDGE(base[2*LCOLS - 2], D3, N3, 0.5f, hmw);   /* SW K2 */         \
        COMBINE;                                                          \
    } while (0)

    // DIAGNOSTIC: run the compute phase REPEAT times. The asm pin on `j`
    // blocks CSE across repeats (addresses re-derived, LDS re-read, math
    // re-done). Result is exactly REPEAT * (single-pass acc); scaled below.
    #pragma unroll 1
    for (int rep = 0; rep < REPEAT; ++rep) {
        asm volatile("" : "+v"(j));
        const float4* b0 = &pack[(i0 * 4) * LCOLS + (j + 2)];
        const float4* b1 = b0 + LCOLS;
        const float4* b2 = b1 + LCOLS;
        const float4* b3 = b2 + LCOLS;
        float4 va0 = b0[0], va1 = b1[0], va2 = b2[0], va3 = b3[0];
        PIXEL(va0, va1, va2,                  b0);
        PIXEL(va1, va2, va3,                  b1);
        PIXEL(va2, va3, b2[2 * LCOLS],        b2);
        PIXEL(va3, b3[LCOLS], b3[2 * LCOLS],  b3);
    }
    acc *= (1.0f / REPEAT);
#undef PIXEL
#undef COMBINE
#undef EDGE

    // Block reduction: wave64 shuffle then cross-wave via LDS.
    #pragma unroll
    for (int o = 32; o > 0; o >>= 1) acc += __shfl_down(acc, o, 64);
    __shared__ float wsum[4];
    int lane = threadIdx.x & 63, wid = threadIdx.x >> 6;
    if (lane == 0) wsum[wid] = acc;
    __syncthreads();
    if (threadIdx.x == 0)
        partials[blockIdx.x] = wsum[0] + wsum[1] + wsum[2] + wsum[3];
}

__global__ __launch_bounds__(256) void scloss_final(
    const float* __restrict__ partials, int n, float* __restrict__ out)
{
    double a = 0.0;
    for (int i = threadIdx.x; i < n; i += 256) a += (double)partials[i];
    __shared__ double sd[256];
    sd[threadIdx.x] = a;
    __syncthreads();
    for (int s = 128; s > 0; s >>= 1) {
        if (threadIdx.x < s) sd[threadIdx.x] += sd[threadIdx.x + s];
        __syncthreads();
    }
    if (threadIdx.x == 0) out[0] = (float)(sd[0] / N_MEAN);
}

extern "C" void kernel_launch(void* const* d_in, const int* in_sizes, int n_in,
                              void* d_out, int out_size, void* d_ws, size_t ws_size,
                              hipStream_t stream) {
    const float* cmap = (const float*)d_in[0];
    const int*   tgt  = (const int*)d_in[1];
    float* out      = (float*)d_out;
    float* partials = (float*)d_ws;

    scloss_main<<<NBLK, 256, 0, stream>>>(cmap, tgt, partials);
    scloss_final<<<1, 256, 0, stream>>>(partials, NBLK, out);
}

// Round 13
// 24.740 us; speedup vs baseline: 2.9354x; 2.9354x over previous
//
#include <hip/hip_runtime.h>

#define IMG_H 512
#define IMG_W 512
#define NB    8
#define TILE  32
#define LROWS 34            // rows tr..tr+33 (owner + 2 halo below)
#define LCOLS 36            // lds col = gc - (tc-2), cols tc-2..tc+33
#define NSLOT 340           // 34 rows * 10 aligned float4-slots (cols tc-4..tc+35)
#define NBLK  (NB * (IMG_H / TILE) * (IMG_W / TILE))   // 2048
#define N_MEAN 16777216.0   // B * 8 dirs * H * W
#define LOG2E 1.44269504f
#define LN2   0.69314718f

__device__ __forceinline__ float frcp(float x){ return __builtin_amdgcn_rcpf(x); }
__device__ __forceinline__ float fexp2(float x){ return __builtin_amdgcn_exp2f(x); }
__device__ __forceinline__ float flog2(float x){ return __builtin_amdgcn_logf(x); }

// Per-pixel pack {s, mw, e', nw}:
//   s  = sigmoid(c_map)
//   mw = (t ? -0.6 : -1.4) * log(sel+1e-4), sel = t ? s : 1-s   (eq-pair num, K=1 weight)
//   e' = (t ? -1 : +1) * exp(-s);  e' == 0  => OOB sentinel
//   nw = (t ? -0.07 : -0.28) * log(sel+1e-4)                    (nbr num, -0.35*k folded)
__device__ __forceinline__ float4 make_pack(float x, int t_, bool ok) {
    if (!ok) return make_float4(0.0f, 0.0f, 0.0f, 0.0f);
    bool  t = t_ != 0;
    float s   = frcp(1.0f + fexp2(x * -LOG2E));
    float sel = t ? s : (1.0f - s);
    float L   = LN2 * flog2(sel + 1e-4f);
    float e   = fexp2(s * -LOG2E);
    return make_float4(s, (t ? -0.6f : -1.4f) * L, t ? -e : e,
                       (t ? -0.07f : -0.28f) * L);
}

// One staged slot -> up to 4 LDS pack entries (cols clipped to 0..35).
__device__ __forceinline__ void write_slot(float4* __restrict__ pack, int s,
                                           float4 c, int4 t, bool ok) {
    int lr = s / 10, c4 = s - lr * 10;
    int cb = 4 * c4 - 2;                 // lds col of element 0
    float4* row = pack + lr * LCOLS;
    if ((unsigned)(cb + 0) < LCOLS) row[cb + 0] = make_pack(c.x, t.x, ok);
    if ((unsigned)(cb + 1) < LCOLS) row[cb + 1] = make_pack(c.y, t.y, ok);
    if ((unsigned)(cb + 2) < LCOLS) row[cb + 2] = make_pack(c.z, t.z, ok);
    if ((unsigned)(cb + 3) < LCOLS) row[cb + 3] = make_pack(c.w, t.w, ok);
}

__global__ __launch_bounds__(256, 8) void scloss_main(
    const float* __restrict__ cmap, const int* __restrict__ tgt,
    float* __restrict__ partials)
{
    __shared__ float4 pack[LROWS * LCOLS];

    const int tilesPerRow = IMG_W / TILE;                 // 16
    const int tilesPerImg = (IMG_H / TILE) * tilesPerRow; // 256
    int blk = blockIdx.x;
    int b   = blk / tilesPerImg;
    int ti  = blk % tilesPerImg;
    int tr  = (ti / tilesPerRow) * TILE;
    int tc  = (ti % tilesPerRow) * TILE;

    const float* cimg = cmap + (size_t)b * (IMG_H * IMG_W);
    const int*   timg = tgt  + (size_t)b * (IMG_H * IMG_W);

    // ---- Staging: 340 aligned float4/int4 slot-pairs, all loads hoisted ----
    {
        const int s0 = threadIdx.x;          // < 340 always
        const int s1 = threadIdx.x + 256;    // valid for threads 0..83
        int lr0 = s0 / 10, c40 = s0 - lr0 * 10;
        int lr1 = s1 / 10, c41 = s1 - lr1 * 10;
        int gr0 = tr + lr0, gc0 = tc + c40 * 4 - 4;
        int gr1 = tr + lr1, gc1 = tc + c41 * 4 - 4;
        bool in1 = s1 < NSLOT;
        bool ok0 = (gr0 < IMG_H) && ((unsigned)gc0 < (unsigned)IMG_W);
        bool ok1 = in1 && (gr1 < IMG_H) && ((unsigned)gc1 < (unsigned)IMG_W);
        float4 c0 = make_float4(0.f,0.f,0.f,0.f), c1 = c0;
        int4   t0 = make_int4(0,0,0,0),           t1 = t0;
        // Issue all 4 wide loads back-to-back: ONE HBM latency exposure.
        if (ok0) {
            size_t o = (size_t)gr0 * IMG_W + gc0;
            c0 = *(const float4*)(cimg + o);
            t0 = *(const int4*)(timg + o);
        }
        if (ok1) {
            size_t o = (size_t)gr1 * IMG_W + gc1;
            c1 = *(const float4*)(cimg + o);
            t1 = *(const int4*)(timg + o);
        }
        write_slot(pack, s0, c0, t0, ok0);
        if (in1) write_slot(pack, s1, c1, t1, ok1);
    }
    __syncthreads();

    int j  = threadIdx.x & 31;
    int i0 = threadIdx.x >> 5;      // 0..7 -> owner rows 4*i0..4*i0+3
    float acc = 0.0f;

// One edge, named-scalar outputs only.
#define EDGE(VB, Dd, Nn, WSK, MK) do {                                    \
        float4 vb  = (VB);                                                \
        bool  tb   = vb.z < 0.0f;                                         \
        bool  qpos = (ta == tb);           /* both targets equal */       \
        bool  qnz  = vb.z != 0.0f;         /* neighbor in bounds */       \
        float ppp  = __builtin_fmaf(sa, vb.x, 1e-4f);                     \
        float ompp = __builtin_fmaf(-sa, vb.x, 1.0001f);                  \
        float argc = (qpos && ta) ? ppp : ompp;                           \
        float lg   = flog2(argc);                                         \
        float E    = fexp2(__builtin_fmaf(ppp, -LOG2E, 1e-4f * LOG2E));   \
        float een  = ta ? vb.z : epa;      /* e' of the t=0 endpoint */   \
        float ee   = qpos ? E : een;                                      \
        Dd         = __builtin_fmaf(-LN2, lg, ee);                        \
        float nm   = qpos ? __builtin_fmaf(WSK, vb.y, MK) : (nwa + vb.w); \
        Nn         = qnz ? nm : 0.0f;                                     \
    } while (0)

// 4 divisions with one reciprocal.
#define COMBINE do {                                                      \
        float d01 = D0 * D1, d23 = D2 * D3;                               \
        float R   = frcp(d01 * d23);                                      \
        float n01 = __builtin_fmaf(N1, D0, N0 * D1);                      \
        float n23 = __builtin_fmaf(N3, D2, N2 * D3);                      \
        acc = __builtin_fmaf(__builtin_fmaf(n23, d01, n01 * d23), R, acc);\
    } while (0)

// One pixel: 8 edges (E,SE,S,SW at K=1,2).
#define PIXEL(VA, S1X, S2X, base) do {                                    \
        float4 va_  = (VA);                                               \
        bool  ta  = va_.z < 0.0f;                                         \
        float sa  = va_.x, nwa = va_.w, epa = va_.z;                      \
        float mwa = va_.y, hmw = 0.5f * va_.y;                            \
        float D0, D1, D2, D3, N0, N1, N2, N3;                             \
        EDGE(base[1],           D0, N0, 1.0f, mwa);   /* E  K1 */         \
        EDGE(base[LCOLS + 1],   D1, N1, 1.0f, mwa);   /* SE K1 */         \
        EDGE(S1X,               D2, N2, 1.0f, mwa);   /* S  K1 */         \
        EDGE(base[LCOLS - 1],   D3, N3, 1.0f, mwa);   /* SW K1 */         \
        COMBINE;                                                          \
        EDGE(base[2],           D0, N0, 0.5f, hmw);   /* E  K2 */         \
        EDGE(base[2*LCOLS + 2], D1, N1, 0.5f, hmw);   /* SE K2 */         \
        EDGE(S2X,               D2, N2, 0.5f, hmw);   /* S  K2 */         \
        EDGE(base[2*LCOLS - 2], D3, N3, 0.5f, hmw);   /* SW K2 */         \
        COMBINE;                                                          \
    } while (0)

    {
        const float4* b0 = &pack[(i0 * 4) * LCOLS + (j + 2)];
        const float4* b1 = b0 + LCOLS;
        const float4* b2 = b1 + LCOLS;
        const float4* b3 = b2 + LCOLS;
        float4 va0 = b0[0], va1 = b1[0], va2 = b2[0], va3 = b3[0];
        PIXEL(va0, va1, va2,                  b0);
        PIXEL(va1, va2, va3,                  b1);
        PIXEL(va2, va3, b2[2 * LCOLS],        b2);
        PIXEL(va3, b3[LCOLS], b3[2 * LCOLS],  b3);
    }
#undef PIXEL
#undef COMBINE
#undef EDGE

    // Block reduction: wave64 shuffle then cross-wave via LDS.
    #pragma unroll
    for (int o = 32; o > 0; o >>= 1) acc += __shfl_down(acc, o, 64);
    __shared__ float wsum[4];
    int lane = threadIdx.x & 63, wid = threadIdx.x >> 6;
    if (lane == 0) wsum[wid] = acc;
    __syncthreads();
    if (threadIdx.x == 0)
        partials[blockIdx.x] = wsum[0] + wsum[1] + wsum[2] + wsum[3];
}

__global__ __launch_bounds__(256) void scloss_final(
    const float* __restrict__ partials, int n, float* __restrict__ out)
{
    double a = 0.0;
    for (int i = threadIdx.x; i < n; i += 256) a += (double)partials[i];
    __shared__ double sd[256];
    sd[threadIdx.x] = a;
    __syncthreads();
    for (int s = 128; s > 0; s >>= 1) {
        if (threadIdx.x < s) sd[threadIdx.x] += sd[threadIdx.x + s];
        __syncthreads();
    }
    if (threadIdx.x == 0) out[0] = (float)(sd[0] / N_MEAN);
}

extern "C" void kernel_launch(void* const* d_in, const int* in_sizes, int n_in,
                              void* d_out, int out_size, void* d_ws, size_t ws_size,
                              hipStream_t stream) {
    const float* cmap = (const float*)d_in[0];
    const int*   tgt  = (const int*)d_in[1];
    float* out      = (float*)d_out;
    float* partials = (float*)d_ws;

    scloss_main<<<NBLK, 256, 0, stream>>>(cmap, tgt, partials);
    scloss_final<<<1, 256, 0, stream>>>(partials, NBLK, out);
}

// Round 14
// 22.128 us; speedup vs baseline: 3.2818x; 1.1180x over previous
//
#include <hip/hip_runtime.h>

#define IMG_H 512
#define IMG_W 512
#define NB    8
#define TILE  32
#define LROWS 34            // rows tr..tr+33 (owner + 2 halo below)
#define LCOLS 36            // lds col = gc - (tc-2), cols tc-2..tc+33
#define NSLOT 340           // 34 rows * 10 aligned float4-slots (cols tc-4..tc+35)
#define NBLK  (NB * (IMG_H / TILE) * (IMG_W / TILE))   // 2048
#define N_MEAN 16777216.0   // B * 8 dirs * H * W
#define LOG2E 1.44269504f
#define LN2   0.69314718f

__device__ __forceinline__ float frcp(float x){ return __builtin_amdgcn_rcpf(x); }
__device__ __forceinline__ float fexp2(float x){ return __builtin_amdgcn_exp2f(x); }
__device__ __forceinline__ float flog2(float x){ return __builtin_amdgcn_logf(x); }

// Per-pixel pack {s, mw, e', nw}:
//   s  = sigmoid(c_map)
//   mw = (t ? -0.6 : -1.4) * log(sel+1e-4), sel = t ? s : 1-s   (eq-pair num, K=1 weight)
//   e' = (t ? -1 : +1) * exp(-s);  e' == 0  => OOB sentinel
//   nw = (t ? -0.07 : -0.28) * log(sel+1e-4)                    (nbr num, -0.35*k folded)
__device__ __forceinline__ float4 make_pack(float x, int t_) {
    bool  t = t_ != 0;
    float s   = frcp(1.0f + fexp2(x * -LOG2E));
    float sel = t ? s : (1.0f - s);
    float L   = LN2 * flog2(sel + 1e-4f);
    float e   = fexp2(s * -LOG2E);
    return make_float4(s, (t ? -0.6f : -1.4f) * L, t ? -e : e,
                       (t ? -0.07f : -0.28f) * L);
}

// One staged slot -> up to 4 LDS pack entries (cols clipped to 0..35).
__device__ __forceinline__ void write_slot(float4* __restrict__ pack, int s,
                                           float4 c, int4 t, bool ok) {
    int lr = s / 10, c4 = s - lr * 10;
    int cb = 4 * c4 - 2;                 // lds col of element 0
    float4* row = pack + lr * LCOLS;
    float4 z = make_float4(0.f, 0.f, 0.f, 0.f);
    if ((unsigned)(cb + 0) < LCOLS) row[cb + 0] = ok ? make_pack(c.x, t.x) : z;
    if ((unsigned)(cb + 1) < LCOLS) row[cb + 1] = ok ? make_pack(c.y, t.y) : z;
    if ((unsigned)(cb + 2) < LCOLS) row[cb + 2] = ok ? make_pack(c.z, t.z) : z;
    if ((unsigned)(cb + 3) < LCOLS) row[cb + 3] = ok ? make_pack(c.w, t.w) : z;
}

// One edge, named-scalar outputs only.  SAFE=1: neighbor known in-bounds.
#define EDGE(VB, Dd, Nn, WSK, MK, SAFE) do {                              \
        float4 vb  = (VB);                                                \
        bool  tb   = vb.z < 0.0f;                                         \
        bool  qpos = (ta == tb);           /* both targets equal */       \
        float ppp  = __builtin_fmaf(sa, vb.x, 1e-4f);                     \
        float ompp = __builtin_fmaf(-sa, vb.x, 1.0001f);                  \
        float argc = (qpos && ta) ? ppp : ompp;                           \
        float lg   = flog2(argc);                                         \
        float E    = fexp2(__builtin_fmaf(ppp, -LOG2E, 1e-4f * LOG2E));   \
        float een  = ta ? vb.z : epa;      /* e' of the t=0 endpoint */   \
        float ee   = qpos ? E : een;                                      \
        Dd         = __builtin_fmaf(-LN2, lg, ee);                        \
        float nm   = qpos ? __builtin_fmaf(WSK, vb.y, MK) : (nwa + vb.w); \
        Nn         = SAFE ? nm : ((vb.z != 0.0f) ? nm : 0.0f);            \
    } while (0)

// 4 divisions with one reciprocal.
#define COMBINE do {                                                      \
        float d01 = D0 * D1, d23 = D2 * D3;                               \
        float R   = frcp(d01 * d23);                                      \
        float n01 = __builtin_fmaf(N1, D0, N0 * D1);                      \
        float n23 = __builtin_fmaf(N3, D2, N2 * D3);                      \
        acc = __builtin_fmaf(__builtin_fmaf(n23, d01, n01 * d23), R, acc);\
    } while (0)

// One pixel: 8 edges (E,SE,S,SW at K=1,2).
#define PIXEL(VA, S1X, S2X, base, SAFE) do {                              \
        float4 va_  = (VA);                                               \
        bool  ta  = va_.z < 0.0f;                                         \
        float sa  = va_.x, nwa = va_.w, epa = va_.z;                      \
        float mwa = va_.y, hmw = 0.5f * va_.y;                            \
        float D0, D1, D2, D3, N0, N1, N2, N3;                             \
        EDGE(base[1],           D0, N0, 1.0f, mwa, SAFE);  /* E  K1 */    \
        EDGE(base[LCOLS + 1],   D1, N1, 1.0f, mwa, SAFE);  /* SE K1 */    \
        EDGE(S1X,               D2, N2, 1.0f, mwa, SAFE);  /* S  K1 */    \
        EDGE(base[LCOLS - 1],   D3, N3, 1.0f, mwa, SAFE);  /* SW K1 */    \
        COMBINE;                                                          \
        EDGE(base[2],           D0, N0, 0.5f, hmw, SAFE);  /* E  K2 */    \
        EDGE(base[2*LCOLS + 2], D1, N1, 0.5f, hmw, SAFE);  /* SE K2 */    \
        EDGE(S2X,               D2, N2, 0.5f, hmw, SAFE);  /* S  K2 */    \
        EDGE(base[2*LCOLS - 2], D3, N3, 0.5f, hmw, SAFE);  /* SW K2 */    \
        COMBINE;                                                          \
    } while (0)

#define COMPUTE_TILE(SAFE) do {                                           \
        const float4* b0 = &pack[(i0 * 4) * LCOLS + (j + 2)];             \
        const float4* b1 = b0 + LCOLS;                                    \
        const float4* b2 = b1 + LCOLS;                                    \
        const float4* b3 = b2 + LCOLS;                                    \
        float4 va0 = b0[0], va1 = b1[0], va2 = b2[0], va3 = b3[0];        \
        PIXEL(va0, va1, va2,                  b0, SAFE);                  \
        PIXEL(va1, va2, va3,                  b1, SAFE);                  \
        PIXEL(va2, va3, b2[2 * LCOLS],        b2, SAFE);                  \
        PIXEL(va3, b3[LCOLS], b3[2 * LCOLS],  b3, SAFE);                  \
    } while (0)

__global__ __launch_bounds__(256, 8) void scloss_main(
    const float* __restrict__ cmap, const int* __restrict__ tgt,
    float* __restrict__ partials)
{
    __shared__ float4 pack[LROWS * LCOLS];

    const int tilesPerRow = IMG_W / TILE;                 // 16
    const int tilesPerImg = (IMG_H / TILE) * tilesPerRow; // 256
    int blk = blockIdx.x;
    int b   = blk / tilesPerImg;
    int ti  = blk % tilesPerImg;
    int tr  = (ti / tilesPerRow) * TILE;
    int tc  = (ti % tilesPerRow) * TILE;

    const float* cimg = cmap + (size_t)b * (IMG_H * IMG_W);
    const int*   timg = tgt  + (size_t)b * (IMG_H * IMG_W);

    // Interior tile: every staged col (tc-4..tc+35) and row (tr..tr+33)
    // in-bounds -> unconditional loads, SAFE compute (no qnz per edge).
    bool interior = (tr <= IMG_H - 2 - TILE) && (tc >= 4) && (tc <= IMG_W - 36);

    const int s0 = threadIdx.x;          // < 340 always
    const int s1 = threadIdx.x + 256;    // valid for threads 0..83
    int lr0 = s0 / 10, c40 = s0 - lr0 * 10;
    int lr1 = s1 / 10, c41 = s1 - lr1 * 10;
    int gr0 = tr + lr0, gc0 = tc + c40 * 4 - 4;
    int gr1 = tr + lr1, gc1 = tc + c41 * 4 - 4;
    bool in1 = s1 < NSLOT;

    int j  = threadIdx.x & 31;
    int i0 = threadIdx.x >> 5;      // 0..7 -> owner rows 4*i0..4*i0+3
    float acc = 0.0f;

    if (interior) {
        size_t o0 = (size_t)gr0 * IMG_W + gc0;
        size_t o1 = (size_t)gr1 * IMG_W + gc1;
        float4 c0 = *(const float4*)(cimg + o0);
        int4   t0 = *(const int4*)(timg + o0);
        float4 c1 = make_float4(0.f,0.f,0.f,0.f);
        int4   t1 = make_int4(0,0,0,0);
        if (in1) { c1 = *(const float4*)(cimg + o1); t1 = *(const int4*)(timg + o1); }
        write_slot(pack, s0, c0, t0, true);
        if (in1) write_slot(pack, s1, c1, t1, true);
        __syncthreads();
        COMPUTE_TILE(true);
    } else {
        bool ok0 = (gr0 < IMG_H) && ((unsigned)gc0 < (unsigned)IMG_W);
        bool ok1 = in1 && (gr1 < IMG_H) && ((unsigned)gc1 < (unsigned)IMG_W);
        float4 c0 = make_float4(0.f,0.f,0.f,0.f), c1 = c0;
        int4   t0 = make_int4(0,0,0,0),           t1 = t0;
        if (ok0) { size_t o = (size_t)gr0 * IMG_W + gc0;
                   c0 = *(const float4*)(cimg + o); t0 = *(const int4*)(timg + o); }
        if (ok1) { size_t o = (size_t)gr1 * IMG_W + gc1;
                   c1 = *(const float4*)(cimg + o); t1 = *(const int4*)(timg + o); }
        write_slot(pack, s0, c0, t0, ok0);
        if (in1) write_slot(pack, s1, c1, t1, ok1);
        __syncthreads();
        COMPUTE_TILE(false);
    }

    // Block reduction: wave64 shuffle then cross-wave via LDS.
    #pragma unroll
    for (int o = 32; o > 0; o >>= 1) acc += __shfl_down(acc, o, 64);
    __shared__ float wsum[4];
    int lane = threadIdx.x & 63, wid = threadIdx.x >> 6;
    if (lane == 0) wsum[wid] = acc;
    __syncthreads();
    if (threadIdx.x == 0)
        partials[blockIdx.x] = wsum[0] + wsum[1] + wsum[2] + wsum[3];
}

// 1-wave final: 2048 partials, 32 strided f64 adds/lane, shfl reduce.
__global__ __launch_bounds__(64) void scloss_final(
    const float* __restrict__ partials, float* __restrict__ out)
{
    double a = 0.0;
    #pragma unroll
    for (int i = 0; i < NBLK / 64; ++i)
        a += (double)partials[i * 64 + threadIdx.x];
    #pragma unroll
    for (int o = 32; o > 0; o >>= 1) a += __shfl_down(a, o, 64);
    if (threadIdx.x == 0) out[0] = (float)(a / N_MEAN);
}

extern "C" void kernel_launch(void* const* d_in, const int* in_sizes, int n_in,
                              void* d_out, int out_size, void* d_ws, size_t ws_size,
                              hipStream_t stream) {
    const float* cmap = (const float*)d_in[0];
    const int*   tgt  = (const int*)d_in[1];
    float* out      = (float*)d_out;
    float* partials = (float*)d_ws;

    scloss_main<<<NBLK, 256, 0, stream>>>(cmap, tgt, partials);
    scloss_final<<<1, 64, 0, stream>>>(partials, out);
}